// Round 2
// baseline (37099.652 us; speedup 1.0000x reference)
//
#include <hip/hip_runtime.h>

#define BB   64
#define TT   1024
#define II   256
#define HH   512
#define NBLK 32
#define NTHR 512
#define SLICE 16
#define WHH_STR 520
#define WIH_STR 264
#define CLIPV 5.0f

typedef __attribute__((ext_vector_type(8))) short short8;
typedef __attribute__((ext_vector_type(4))) float f32x4;
typedef unsigned long long u64;

// ---------- bf16 helpers (RNE) ----------
__device__ __forceinline__ unsigned short f2bf(float f){
    unsigned u = __float_as_uint(f);
    u += 0x7fffu + ((u >> 16) & 1u);
    return (unsigned short)(u >> 16);
}
__device__ __forceinline__ float bf2f(unsigned short s){
    return __uint_as_float(((unsigned)s) << 16);
}
// split fp32 -> (hi,lo) bf16 pair packed in one dword (hi in low 16)
__device__ __forceinline__ unsigned packsplit(float f){
    unsigned short hi = f2bf(f);
    unsigned short lo = f2bf(f - bf2f(hi));
    return (unsigned)hi | ((unsigned)lo << 16);
}

__device__ __forceinline__ void unpack8(const uint4 a, const uint4 b, short8 &hi, short8 &lo){
    hi[0]=(short)a.x; lo[0]=(short)(a.x>>16);
    hi[1]=(short)a.y; lo[1]=(short)(a.y>>16);
    hi[2]=(short)a.z; lo[2]=(short)(a.z>>16);
    hi[3]=(short)a.w; lo[3]=(short)(a.w>>16);
    hi[4]=(short)b.x; lo[4]=(short)(b.x>>16);
    hi[5]=(short)b.y; lo[5]=(short)(b.y>>16);
    hi[6]=(short)b.z; lo[6]=(short)(b.z>>16);
    hi[7]=(short)b.w; lo[7]=(short)(b.w>>16);
}

#define SPLIT1(f, j) { float f_=(f); unsigned short h_=f2bf(f_); hi[j]=(short)h_; lo[j]=(short)f2bf(f_-bf2f(h_)); }
__device__ __forceinline__ void split8(const float4 a, const float4 b, short8 &hi, short8 &lo){
    SPLIT1(a.x,0) SPLIT1(a.y,1) SPLIT1(a.z,2) SPLIT1(a.w,3)
    SPLIT1(b.x,4) SPLIT1(b.y,5) SPLIT1(b.z,6) SPLIT1(b.w,7)
}
#undef SPLIT1

__device__ __forceinline__ f32x4 mfma(short8 a, short8 b, f32x4 c){
    return __builtin_amdgcn_mfma_f32_16x16x32_bf16(a, b, c, 0, 0, 0);
}

// ---------- relaxed agent-scope (sc1 / LLC-coherent) primitives ----------
__device__ __forceinline__ u64 ld64(const u64* p){
    return __hip_atomic_load((u64*)p, __ATOMIC_RELAXED, __HIP_MEMORY_SCOPE_AGENT);
}
__device__ __forceinline__ void st32(unsigned* p, unsigned v){
    __hip_atomic_store(p, v, __ATOMIC_RELAXED, __HIP_MEMORY_SCOPE_AGENT);
}
__device__ __forceinline__ unsigned ldflag(const unsigned* p){
    return __hip_atomic_load((unsigned*)p, __ATOMIC_RELAXED, __HIP_MEMORY_SCOPE_AGENT);
}
__device__ __forceinline__ void addflag(unsigned* p){
    __hip_atomic_fetch_add(p, 1u, __ATOMIC_RELAXED, __HIP_MEMORY_SCOPE_AGENT);
}
// drain own wave's outstanding vmem+lds before signaling
__device__ __forceinline__ void drain(){
    asm volatile("s_waitcnt vmcnt(0) lgkmcnt(0)" ::: "memory");
}

// all-block flag barrier: relaxed polls, no per-iteration cache maintenance
__device__ __forceinline__ void wait_flags(const unsigned* f, unsigned target){
    const unsigned* p = f + (threadIdx.x & 31);
    while (true){
        unsigned v = ldflag(p);
        if (__all((int)(v >= target))) break;
    }
    asm volatile("" ::: "memory");  // compiler barrier only
}

#define LDS_BYTES ((48*WHH_STR + 48*WIH_STR)*2*2 + 64*4 + 1024*4 + 1024*4)

extern "C" __global__ void pack_x_kernel(const float* __restrict__ x,
                                         unsigned* __restrict__ xp, int n){
    int idx = blockIdx.x * 256 + threadIdx.x;
    if (idx < n) xp[idx] = packsplit(x[idx]);
}

extern "C" __global__ void __launch_bounds__(NTHR, 1) gru_scan(
    const float* __restrict__ x,  const float* __restrict__ h0,
    const float* __restrict__ Wih, const float* __restrict__ bih,
    const float* __restrict__ Whh, const float* __restrict__ bhh,
    float* __restrict__ out, unsigned* __restrict__ ws,
    const unsigned* __restrict__ xp)
{
    extern __shared__ char smem[];
    unsigned short* whh_hi = (unsigned short*)smem;                // 48 x WHH_STR
    unsigned short* whh_lo = whh_hi + 48*WHH_STR;
    unsigned short* wih_hi = whh_lo + 48*WHH_STR;                  // 48 x WIH_STR
    unsigned short* wih_lo = wih_hi + 48*WIH_STR;
    float* biasL = (float*)(wih_lo + 48*WIH_STR);                  // 48 (padded 64)
    float* nh1   = biasL + 64;                                     // 64x16 fp32
    float* h_own = nh1 + 1024;                                     // 64x16 fp32 (own h cols)

    unsigned* flagA = ws;           // 32 flags
    unsigned* flagB = ws + 32;      // 32 flags
    unsigned* hp    = ws + 128;     // packed h pairs, 64x512 dwords
    unsigned* rhp   = hp + BB*HH;   // packed r*h pairs

    const int tid = threadIdx.x;
    const int bb  = blockIdx.x;
    const int colBase = SLICE * bb;

    // ---- load weight slices to LDS as bf16 pairs ----
    for (int e = tid; e < 48*HH; e += NTHR){
        int r = e >> 9, k = e & (HH-1);
        int g = r >> 4, j = r & 15;
        int grow = g*HH + colBase + j;
        float v = Whh[grow*HH + k];
        unsigned short hv = f2bf(v);
        whh_hi[r*WHH_STR + k] = hv;
        whh_lo[r*WHH_STR + k] = f2bf(v - bf2f(hv));
    }
    for (int e = tid; e < 48*II; e += NTHR){
        int r = e >> 8, k = e & (II-1);
        int g = r >> 4, j = r & 15;
        int grow = g*HH + colBase + j;
        float v = Wih[grow*II + k];
        unsigned short hv = f2bf(v);
        wih_hi[r*WIH_STR + k] = hv;
        wih_lo[r*WIH_STR + k] = f2bf(v - bf2f(hv));
    }
    if (tid < 48){
        int g = tid >> 4, j = tid & 15;
        int grow = g*HH + colBase + j;
        biasL[tid] = bih[grow] + bhh[grow];
    }
    // ---- publish initial h slice (sc1 relaxed stores) + own-col LDS copy ----
    for (int e = tid; e < BB*SLICE; e += NTHR){
        int m = e >> 4, c = e & 15;
        float v = h0[m*HH + colBase + c];
        st32(hp + m*HH + colBase + c, packsplit(v));
        h_own[m*16 + c] = v;
    }
    __syncthreads();     // drains vmem for all waves; LDS init visible
    if ((tid & 63) == 0) addflag(flagB + bb);   // 8 waves -> flagB[bb] = 8

    const int w = tid >> 6, lane = tid & 63;
    const int quad = lane >> 4, li = lane & 15;
    const int g = w >> 2, mt = w & 3;       // g: 0=z(+nx), 1=r ; phase B: K-half = g
    const int am  = mt*16 + li;             // A-frag batch row
    const int cg  = colBase + li;           // owned gate column
    const int dm0 = mt*16 + quad*4;         // D-layout batch rows base

    float hprev[4];                          // own h (g0 threads use for z-blend)
    #pragma unroll
    for (int i = 0; i < 4; ++i) hprev[i] = h0[(size_t)(dm0+i)*HH + cg];

    float zh[4], omz[4];
    f32x4 accNX;

    for (int t = 0; t < TT; ++t){
        // ======== x prefetch + x-part MFMA (independent of h: before wait) ====
        f32x4 accG = {0.f,0.f,0.f,0.f};
        accNX = (f32x4){0.f,0.f,0.f,0.f};
        {
            uint4 xbuf[16];
            const char* xb;
            if (xp) xb = (const char*)(xp + ((size_t)am*TT + t)*II + quad*8);
            else    xb = (const char*)(x  + ((size_t)am*TT + t)*II + quad*8);
            #pragma unroll
            for (int kt = 0; kt < 8; ++kt){
                xbuf[2*kt]   = *(const uint4*)(xb + (size_t)kt*128);
                xbuf[2*kt+1] = *(const uint4*)(xb + (size_t)kt*128 + 16);
            }
            #pragma unroll
            for (int kt = 0; kt < 8; ++kt){
                short8 ah, al;
                if (xp) unpack8(xbuf[2*kt], xbuf[2*kt+1], ah, al);
                else {
                    float4 f0 = *(const float4*)&xbuf[2*kt];
                    float4 f1 = *(const float4*)&xbuf[2*kt+1];
                    split8(f0, f1, ah, al);
                }
                int ko = kt*32 + quad*8;
                short8 bh = *(const short8*)(wih_hi + (g*16+li)*WIH_STR + ko);
                short8 bl = *(const short8*)(wih_lo + (g*16+li)*WIH_STR + ko);
                accG = mfma(ah, bh, accG);
                accG = mfma(ah, bl, accG);
                accG = mfma(al, bh, accG);
                if (g == 0){
                    short8 nbh = *(const short8*)(wih_hi + (32+li)*WIH_STR + ko);
                    short8 nbl = *(const short8*)(wih_lo + (32+li)*WIH_STR + ko);
                    accNX = mfma(ah, nbh, accNX);
                    accNX = mfma(ah, nbl, accNX);
                    accNX = mfma(al, nbh, accNX);
                }
            }
        }

        // ================= phase A : wait h, z/r h-matmul =================
        wait_flags(flagB, (unsigned)(8*(t+1)));

        {
            u64 hb[64];
            const u64* hrow = (const u64*)(hp + (size_t)am*HH) + quad*4;
            #pragma unroll
            for (int k4 = 0; k4 < 64; ++k4){
                int kt = k4 >> 2, j = k4 & 3;
                hb[k4] = ld64(hrow + kt*16 + j);
            }
            #pragma unroll
            for (int kt = 0; kt < 16; ++kt){
                short8 ah, al;
                #pragma unroll
                for (int j = 0; j < 4; ++j){
                    u64 v = hb[kt*4+j];
                    unsigned d0 = (unsigned)v, d1 = (unsigned)(v >> 32);
                    ah[2*j]   = (short)d0;  al[2*j]   = (short)(d0 >> 16);
                    ah[2*j+1] = (short)d1;  al[2*j+1] = (short)(d1 >> 16);
                }
                int ko = kt*32 + quad*8;
                short8 bh = *(const short8*)(whh_hi + (g*16+li)*WHH_STR + ko);
                short8 bl = *(const short8*)(whh_lo + (g*16+li)*WHH_STR + ko);
                accG = mfma(ah, bh, accG);
                accG = mfma(ah, bl, accG);
                accG = mfma(al, bh, accG);
            }
        }
        {
            float bsum = biasL[g*16 + li];
            #pragma unroll
            for (int i = 0; i < 4; ++i){
                float gate = 1.f/(1.f + __expf(-(accG[i] + bsum)));
                if (g == 0){
                    zh[i] = gate*hprev[i]; omz[i] = 1.f - gate;
                } else {
                    float hvf = h_own[(dm0+i)*16 + li];
                    st32(rhp + (size_t)(dm0+i)*HH + cg, packsplit(gate*hvf));
                }
            }
        }
        drain();
        if (lane == 0) addflag(flagA + bb);

        // ================= phase B : n, blend, publish h =================
        wait_flags(flagA, (unsigned)(8*(t+1)));
        f32x4 accN = (g == 0) ? accNX : (f32x4){0.f,0.f,0.f,0.f};
        {
            u64 rb[32];
            const u64* rrow = (const u64*)(rhp + (size_t)am*HH) + quad*4 + (size_t)g*8*16;
            #pragma unroll
            for (int k4 = 0; k4 < 32; ++k4){
                int kt8 = k4 >> 2, j = k4 & 3;
                rb[k4] = ld64(rrow + kt8*16 + j);
            }
            #pragma unroll
            for (int kt8 = 0; kt8 < 8; ++kt8){
                short8 ah, al;
                #pragma unroll
                for (int j = 0; j < 4; ++j){
                    u64 v = rb[kt8*4+j];
                    unsigned d0 = (unsigned)v, d1 = (unsigned)(v >> 32);
                    ah[2*j]   = (short)d0;  al[2*j]   = (short)(d0 >> 16);
                    ah[2*j+1] = (short)d1;  al[2*j+1] = (short)(d1 >> 16);
                }
                int kt = g*8 + kt8;
                int ko = kt*32 + quad*8;
                short8 bh = *(const short8*)(whh_hi + (32+li)*WHH_STR + ko);
                short8 bl = *(const short8*)(whh_lo + (32+li)*WHH_STR + ko);
                accN = mfma(ah, bh, accN);
                accN = mfma(ah, bl, accN);
                accN = mfma(al, bh, accN);
            }
        }
        if (g == 1){
            #pragma unroll
            for (int i = 0; i < 4; ++i) nh1[(dm0+i)*16 + li] = accN[i];
        }
        __syncthreads();   // nh1 handoff g1 -> g0 (few pending ops: cheap drain)
        if (g == 0){
            float bn = biasL[32 + li];
            #pragma unroll
            for (int i = 0; i < 4; ++i){
                float np = accN[i] + nh1[(dm0+i)*16 + li] + bn;
                float n  = tanhf(np);
                float hv = zh[i] + omz[i]*n;
                hv = fminf(fmaxf(hv, -CLIPV), CLIPV);
                out[((size_t)(dm0+i)*TT + t)*HH + cg] = hv;
                if (t == TT-1) out[(size_t)BB*TT*HH + (size_t)(dm0+i)*HH + cg] = hv;
                st32(hp + (size_t)(dm0+i)*HH + cg, packsplit(hv));
                h_own[(dm0+i)*16 + li] = hv;
                hprev[i] = hv;
            }
        }
        drain();
        if (lane == 0) addflag(flagB + bb);
    }
}

extern "C" void kernel_launch(void* const* d_in, const int* in_sizes, int n_in,
                              void* d_out, int out_size, void* d_ws, size_t ws_size,
                              hipStream_t stream) {
    const float* x   = (const float*)d_in[0];
    const float* h0  = (const float*)d_in[1];
    const float* Wih = (const float*)d_in[2];
    const float* bih = (const float*)d_in[3];
    const float* Whh = (const float*)d_in[4];
    const float* bhh = (const float*)d_in[5];
    float* out = (float*)d_out;
    unsigned* ws = (unsigned*)d_ws;

    // ws layout: [flags 512B][hp 128KB][rhp 128KB][optional packed x 64MB]
    const size_t base_bytes = 512 + 2*(size_t)BB*HH*4;
    const size_t xp_bytes   = (size_t)BB*TT*II*4;
    unsigned* xp = nullptr;
    if (ws_size >= base_bytes + xp_bytes){
        xp = ws + base_bytes/4;
        int n = BB*TT*II;
        pack_x_kernel<<<dim3((n + 255)/256), dim3(256), 0, stream>>>(x, xp, n);
    }
    hipMemsetAsync(d_ws, 0, 512, stream);  // zero barrier flags every launch
    (void)hipFuncSetAttribute((const void*)gru_scan,
                              hipFuncAttributeMaxDynamicSharedMemorySize,
                              (int)LDS_BYTES);
    gru_scan<<<dim3(NBLK), dim3(NTHR), LDS_BYTES, stream>>>(
        x, h0, Wih, bih, Whh, bhh, out, ws, xp);
}

// Round 3
// 28035.916 us; speedup vs baseline: 1.3233x; 1.3233x over previous
//
#include <hip/hip_runtime.h>

#define BB   64
#define TT   1024
#define II   256
#define HH   512
#define NBLK 32
#define NTHR 512
#define SLICE 16
#define WHH_STR 520
#define WIH_STR 264
#define CLIPV 5.0f
#define FSTR 32            // dwords between flags: one flag per 128-B line

typedef __attribute__((ext_vector_type(8))) short short8;
typedef __attribute__((ext_vector_type(4))) float f32x4;
typedef unsigned long long u64;

// ---------- bf16 helpers (RNE) ----------
__device__ __forceinline__ unsigned short f2bf(float f){
    unsigned u = __float_as_uint(f);
    u += 0x7fffu + ((u >> 16) & 1u);
    return (unsigned short)(u >> 16);
}
__device__ __forceinline__ float bf2f(unsigned short s){
    return __uint_as_float(((unsigned)s) << 16);
}
// split fp32 -> (hi,lo) bf16 pair packed in one dword (hi in low 16)
__device__ __forceinline__ unsigned packsplit(float f){
    unsigned short hi = f2bf(f);
    unsigned short lo = f2bf(f - bf2f(hi));
    return (unsigned)hi | ((unsigned)lo << 16);
}

__device__ __forceinline__ void unpack8(const uint4 a, const uint4 b, short8 &hi, short8 &lo){
    hi[0]=(short)a.x; lo[0]=(short)(a.x>>16);
    hi[1]=(short)a.y; lo[1]=(short)(a.y>>16);
    hi[2]=(short)a.z; lo[2]=(short)(a.z>>16);
    hi[3]=(short)a.w; lo[3]=(short)(a.w>>16);
    hi[4]=(short)b.x; lo[4]=(short)(b.x>>16);
    hi[5]=(short)b.y; lo[5]=(short)(b.y>>16);
    hi[6]=(short)b.z; lo[6]=(short)(b.z>>16);
    hi[7]=(short)b.w; lo[7]=(short)(b.w>>16);
}

#define SPLIT1(f, j) { float f_=(f); unsigned short h_=f2bf(f_); hi[j]=(short)h_; lo[j]=(short)f2bf(f_-bf2f(h_)); }
__device__ __forceinline__ void split8(const float4 a, const float4 b, short8 &hi, short8 &lo){
    SPLIT1(a.x,0) SPLIT1(a.y,1) SPLIT1(a.z,2) SPLIT1(a.w,3)
    SPLIT1(b.x,4) SPLIT1(b.y,5) SPLIT1(b.z,6) SPLIT1(b.w,7)
}
#undef SPLIT1

__device__ __forceinline__ f32x4 mfma(short8 a, short8 b, f32x4 c){
    return __builtin_amdgcn_mfma_f32_16x16x32_bf16(a, b, c, 0, 0, 0);
}

// ---------- relaxed agent-scope (LLC-coherent) primitives ----------
__device__ __forceinline__ u64 ld64(const u64* p){
    return __hip_atomic_load((u64*)p, __ATOMIC_RELAXED, __HIP_MEMORY_SCOPE_AGENT);
}
__device__ __forceinline__ void st32(unsigned* p, unsigned v){
    __hip_atomic_store(p, v, __ATOMIC_RELAXED, __HIP_MEMORY_SCOPE_AGENT);
}
__device__ __forceinline__ unsigned ldflag(const unsigned* p){
    return __hip_atomic_load((unsigned*)p, __ATOMIC_RELAXED, __HIP_MEMORY_SCOPE_AGENT);
}

// all-block flag barrier: flags spread one per 128-B line; single-writer epochs;
// lane L polls line (L&31); light s_sleep throttle keeps LLC banks unsaturated.
__device__ __forceinline__ void wait_flags(const unsigned* f, unsigned target){
    const unsigned* p = f + (threadIdx.x & 31) * FSTR;
    while (true){
        unsigned v = ldflag(p);
        if (__all((int)(v >= target))) break;
        __builtin_amdgcn_s_sleep(1);
    }
    asm volatile("" ::: "memory");  // compiler barrier only
}

#define LDS_BYTES ((48*WHH_STR + 48*WIH_STR)*2*2 + 64*4 + 1024*4 + 1024*4)

extern "C" __global__ void pack_x_kernel(const float* __restrict__ x,
                                         unsigned* __restrict__ xp, int n){
    int idx = blockIdx.x * 256 + threadIdx.x;
    if (idx < n) xp[idx] = packsplit(x[idx]);
}

extern "C" __global__ void __launch_bounds__(NTHR, 1) gru_scan(
    const float* __restrict__ x,  const float* __restrict__ h0,
    const float* __restrict__ Wih, const float* __restrict__ bih,
    const float* __restrict__ Whh, const float* __restrict__ bhh,
    float* __restrict__ out, unsigned* __restrict__ ws,
    const unsigned* __restrict__ xp)
{
    extern __shared__ char smem[];
    unsigned short* whh_hi = (unsigned short*)smem;                // 48 x WHH_STR
    unsigned short* whh_lo = whh_hi + 48*WHH_STR;
    unsigned short* wih_hi = whh_lo + 48*WHH_STR;                  // 48 x WIH_STR
    unsigned short* wih_lo = wih_hi + 48*WIH_STR;
    float* biasL = (float*)(wih_lo + 48*WIH_STR);                  // 48 (padded 64)
    float* nh1   = biasL + 64;                                     // 64x16 fp32
    float* h_own = nh1 + 1024;                                     // 64x16 fp32 (own h cols)

    unsigned* flagA = ws;                   // 32 flags, stride FSTR (32 lines)
    unsigned* flagB = ws + 32*FSTR;         // 32 flags, stride FSTR
    unsigned* hp    = ws + 64*FSTR;         // packed h pairs, 64x512 dwords
    unsigned* rhp   = hp + BB*HH;           // packed r*h pairs

    const int tid = threadIdx.x;
    const int bb  = blockIdx.x;
    const int colBase = SLICE * bb;

    // ---- load weight slices to LDS as bf16 pairs ----
    for (int e = tid; e < 48*HH; e += NTHR){
        int r = e >> 9, k = e & (HH-1);
        int g = r >> 4, j = r & 15;
        int grow = g*HH + colBase + j;
        float v = Whh[grow*HH + k];
        unsigned short hv = f2bf(v);
        whh_hi[r*WHH_STR + k] = hv;
        whh_lo[r*WHH_STR + k] = f2bf(v - bf2f(hv));
    }
    for (int e = tid; e < 48*II; e += NTHR){
        int r = e >> 8, k = e & (II-1);
        int g = r >> 4, j = r & 15;
        int grow = g*HH + colBase + j;
        float v = Wih[grow*II + k];
        unsigned short hv = f2bf(v);
        wih_hi[r*WIH_STR + k] = hv;
        wih_lo[r*WIH_STR + k] = f2bf(v - bf2f(hv));
    }
    if (tid < 48){
        int g = tid >> 4, j = tid & 15;
        int grow = g*HH + colBase + j;
        biasL[tid] = bih[grow] + bhh[grow];
    }
    // ---- publish initial h slice (sc1 relaxed stores) + own-col LDS copy ----
    for (int e = tid; e < BB*SLICE; e += NTHR){
        int m = e >> 4, c = e & 15;
        float v = h0[m*HH + colBase + c];
        st32(hp + m*HH + colBase + c, packsplit(v));
        h_own[m*16 + c] = v;
    }
    __syncthreads();     // drains all waves' vmem; LDS init visible
    if (tid == 0) st32(flagB + bb*FSTR, 1u);

    const int w = tid >> 6, lane = tid & 63;
    const int quad = lane >> 4, li = lane & 15;
    const int g = w >> 2, mt = w & 3;       // g: 0=z(+nx), 1=r ; phase B: K-half = g
    const int am  = mt*16 + li;             // A-frag batch row
    const int cg  = colBase + li;           // owned gate column
    const int dm0 = mt*16 + quad*4;         // D-layout batch rows base

    float hprev[4];                          // own h (g0 threads use for z-blend)
    #pragma unroll
    for (int i = 0; i < 4; ++i) hprev[i] = h0[(size_t)(dm0+i)*HH + cg];

    float zh[4], omz[4];
    f32x4 accNX;

    for (int t = 0; t < TT; ++t){
        // ======== x prefetch + x-part MFMA (independent of h: before wait) ====
        f32x4 accG = {0.f,0.f,0.f,0.f};
        accNX = (f32x4){0.f,0.f,0.f,0.f};
        {
            uint4 xbuf[16];
            const char* xb;
            if (xp) xb = (const char*)(xp + ((size_t)am*TT + t)*II + quad*8);
            else    xb = (const char*)(x  + ((size_t)am*TT + t)*II + quad*8);
            #pragma unroll
            for (int kt = 0; kt < 8; ++kt){
                xbuf[2*kt]   = *(const uint4*)(xb + (size_t)kt*128);
                xbuf[2*kt+1] = *(const uint4*)(xb + (size_t)kt*128 + 16);
            }
            #pragma unroll
            for (int kt = 0; kt < 8; ++kt){
                short8 ah, al;
                if (xp) unpack8(xbuf[2*kt], xbuf[2*kt+1], ah, al);
                else {
                    float4 f0 = *(const float4*)&xbuf[2*kt];
                    float4 f1 = *(const float4*)&xbuf[2*kt+1];
                    split8(f0, f1, ah, al);
                }
                int ko = kt*32 + quad*8;
                short8 bh = *(const short8*)(wih_hi + (g*16+li)*WIH_STR + ko);
                short8 bl = *(const short8*)(wih_lo + (g*16+li)*WIH_STR + ko);
                accG = mfma(ah, bh, accG);
                accG = mfma(ah, bl, accG);
                accG = mfma(al, bh, accG);
                if (g == 0){
                    short8 nbh = *(const short8*)(wih_hi + (32+li)*WIH_STR + ko);
                    short8 nbl = *(const short8*)(wih_lo + (32+li)*WIH_STR + ko);
                    accNX = mfma(ah, nbh, accNX);
                    accNX = mfma(ah, nbl, accNX);
                    accNX = mfma(al, nbh, accNX);
                }
            }
        }

        // ================= phase A : wait h, z/r h-matmul =================
        wait_flags(flagB, (unsigned)(t+1));

        {
            u64 hb[64];
            const u64* hrow = (const u64*)(hp + (size_t)am*HH) + quad*4;
            #pragma unroll
            for (int k4 = 0; k4 < 64; ++k4){
                int kt = k4 >> 2, j = k4 & 3;
                hb[k4] = ld64(hrow + kt*16 + j);
            }
            #pragma unroll
            for (int kt = 0; kt < 16; ++kt){
                short8 ah, al;
                #pragma unroll
                for (int j = 0; j < 4; ++j){
                    u64 v = hb[kt*4+j];
                    unsigned d0 = (unsigned)v, d1 = (unsigned)(v >> 32);
                    ah[2*j]   = (short)d0;  al[2*j]   = (short)(d0 >> 16);
                    ah[2*j+1] = (short)d1;  al[2*j+1] = (short)(d1 >> 16);
                }
                int ko = kt*32 + quad*8;
                short8 bh = *(const short8*)(whh_hi + (g*16+li)*WHH_STR + ko);
                short8 bl = *(const short8*)(whh_lo + (g*16+li)*WHH_STR + ko);
                accG = mfma(ah, bh, accG);
                accG = mfma(ah, bl, accG);
                accG = mfma(al, bh, accG);
            }
        }
        {
            float bsum = biasL[g*16 + li];
            #pragma unroll
            for (int i = 0; i < 4; ++i){
                float gate = 1.f/(1.f + __expf(-(accG[i] + bsum)));
                if (g == 0){
                    zh[i] = gate*hprev[i]; omz[i] = 1.f - gate;
                } else {
                    float hvf = h_own[(dm0+i)*16 + li];
                    st32(rhp + (size_t)(dm0+i)*HH + cg, packsplit(gate*hvf));
                }
            }
        }
        __syncthreads();                    // drains all waves' rhp stores
        if (tid == 0) st32(flagA + bb*FSTR, (unsigned)(t+1));

        // ================= phase B : n, blend, publish h =================
        wait_flags(flagA, (unsigned)(t+1));
        f32x4 accN = (g == 0) ? accNX : (f32x4){0.f,0.f,0.f,0.f};
        {
            u64 rb[32];
            const u64* rrow = (const u64*)(rhp + (size_t)am*HH) + quad*4 + (size_t)g*8*16;
            #pragma unroll
            for (int k4 = 0; k4 < 32; ++k4){
                int kt8 = k4 >> 2, j = k4 & 3;
                rb[k4] = ld64(rrow + kt8*16 + j);
            }
            #pragma unroll
            for (int kt8 = 0; kt8 < 8; ++kt8){
                short8 ah, al;
                #pragma unroll
                for (int j = 0; j < 4; ++j){
                    u64 v = rb[kt8*4+j];
                    unsigned d0 = (unsigned)v, d1 = (unsigned)(v >> 32);
                    ah[2*j]   = (short)d0;  al[2*j]   = (short)(d0 >> 16);
                    ah[2*j+1] = (short)d1;  al[2*j+1] = (short)(d1 >> 16);
                }
                int kt = g*8 + kt8;
                int ko = kt*32 + quad*8;
                short8 bh = *(const short8*)(whh_hi + (32+li)*WHH_STR + ko);
                short8 bl = *(const short8*)(whh_lo + (32+li)*WHH_STR + ko);
                accN = mfma(ah, bh, accN);
                accN = mfma(ah, bl, accN);
                accN = mfma(al, bh, accN);
            }
        }
        if (g == 1){
            #pragma unroll
            for (int i = 0; i < 4; ++i) nh1[(dm0+i)*16 + li] = accN[i];
        }
        __syncthreads();   // nh1 handoff g1 -> g0
        float hv4[4];
        if (g == 0){
            float bn = biasL[32 + li];
            #pragma unroll
            for (int i = 0; i < 4; ++i){
                float np = accN[i] + nh1[(dm0+i)*16 + li] + bn;
                float n  = tanhf(np);
                float hv = zh[i] + omz[i]*n;
                hv = fminf(fmaxf(hv, -CLIPV), CLIPV);
                hv4[i] = hv;
                st32(hp + (size_t)(dm0+i)*HH + cg, packsplit(hv));
                h_own[(dm0+i)*16 + li] = hv;
                hprev[i] = hv;
            }
        }
        __syncthreads();                    // drains g0's hp stores (all waves)
        if (tid == 0) st32(flagB + bb*FSTR, (unsigned)(t+2));
        if (g == 0){
            // HBM output stores AFTER the signal: off the critical path
            #pragma unroll
            for (int i = 0; i < 4; ++i){
                out[((size_t)(dm0+i)*TT + t)*HH + cg] = hv4[i];
                if (t == TT-1) out[(size_t)BB*TT*HH + (size_t)(dm0+i)*HH + cg] = hv4[i];
            }
        }
    }
}

extern "C" void kernel_launch(void* const* d_in, const int* in_sizes, int n_in,
                              void* d_out, int out_size, void* d_ws, size_t ws_size,
                              hipStream_t stream) {
    const float* x   = (const float*)d_in[0];
    const float* h0  = (const float*)d_in[1];
    const float* Wih = (const float*)d_in[2];
    const float* bih = (const float*)d_in[3];
    const float* Whh = (const float*)d_in[4];
    const float* bhh = (const float*)d_in[5];
    float* out = (float*)d_out;
    unsigned* ws = (unsigned*)d_ws;

    // ws layout: [flags 8KB (64 lines)][hp 128KB][rhp 128KB][optional packed x 64MB]
    const size_t flag_bytes = 64*FSTR*4;
    const size_t base_bytes = flag_bytes + 2*(size_t)BB*HH*4;
    const size_t xp_bytes   = (size_t)BB*TT*II*4;
    unsigned* xp = nullptr;
    if (ws_size >= base_bytes + xp_bytes){
        xp = ws + base_bytes/4;
        int n = BB*TT*II;
        pack_x_kernel<<<dim3((n + 255)/256), dim3(256), 0, stream>>>(x, xp, n);
    }
    hipMemsetAsync(d_ws, 0, flag_bytes, stream);  // zero barrier flags every launch
    (void)hipFuncSetAttribute((const void*)gru_scan,
                              hipFuncAttributeMaxDynamicSharedMemorySize,
                              (int)LDS_BYTES);
    gru_scan<<<dim3(NBLK), dim3(NTHR), LDS_BYTES, stream>>>(
        x, h0, Wih, bih, Whh, bhh, out, ws, xp);
}